// Round 5
// baseline (741.285 us; speedup 1.0000x reference)
//
#include <hip/hip_runtime.h>

#define B_   8
#define C_   512
#define HW_  2304
#define BM   128
#define BN   128
#define BK   64
#define NT_  (HW_ / BN)      // 18
#define MCHUNKS 18           // one m-tile per block

typedef __bf16 bf16x8 __attribute__((ext_vector_type(8)));
typedef float  f32x16 __attribute__((ext_vector_type(16)));

__device__ __forceinline__ unsigned short f2bf(float f) {
  unsigned int u = __float_as_uint(f);
  u += 0x7FFF + ((u >> 16) & 1);   // round-to-nearest-even
  return (unsigned short)(u >> 16);
}

__device__ __forceinline__ void gload_lds16(const void* g, void* l) {
  __builtin_amdgcn_global_load_lds(
      (const __attribute__((address_space(1))) unsigned int*)g,
      (__attribute__((address_space(3))) unsigned int*)l, 16, 0, 0);
}

__global__ void zero_out(float* __restrict__ out, int n) {
  int i = blockIdx.x * 256 + threadIdx.x;
  if (i < n) out[i] = 0.0f;
}

// Fused: key fp32 [b][c][n] -> keyT bf16 [b][n][c], plus coarse partial dots
// (fp32, atomicAdd into pre-zeroed out channels 4..9).
__global__ void transpose_coarse(const float* __restrict__ key,
                                 const float* __restrict__ v0, const float* __restrict__ v1,
                                 const float* __restrict__ v2, const float* __restrict__ v3,
                                 const float* __restrict__ v4, const float* __restrict__ v5,
                                 unsigned short* __restrict__ keyT,
                                 float* __restrict__ out) {
  __shared__ float tile[32][33];
  __shared__ float red2[6][8][32];
  int b  = blockIdx.z;
  int n0 = blockIdx.x * 32;
  int c0 = blockIdx.y * 32;
  int tx = threadIdx.x;  // 0..31
  int ty = threadIdx.y;  // 0..7
#pragma unroll
  for (int i = 0; i < 4; i++) {
    int c = c0 + ty + i * 8;
    tile[ty + i * 8][tx] = key[(size_t)b * C_ * HW_ + (size_t)c * HW_ + n0 + tx];
  }
  __syncthreads();
#pragma unroll
  for (int i = 0; i < 4; i++) {
    int n = n0 + ty + i * 8;
    keyT[(size_t)b * HW_ * C_ + (size_t)n * C_ + c0 + tx] = f2bf(tile[tx][ty + i * 8]);
  }
  float s[6] = {0.f, 0.f, 0.f, 0.f, 0.f, 0.f};
#pragma unroll
  for (int i = 0; i < 4; i++) {
    int cr = ty * 4 + i;
    int c  = c0 + cr;
    float kv = tile[cr][tx];
    s[0] += v0[b * C_ + c] * kv;
    s[1] += v1[b * C_ + c] * kv;
    s[2] += v2[b * C_ + c] * kv;
    s[3] += v3[b * C_ + c] * kv;
    s[4] += v4[b * C_ + c] * kv;
    s[5] += v5[b * C_ + c] * kv;
  }
#pragma unroll
  for (int j = 0; j < 6; j++) red2[j][ty][tx] = s[j];
  __syncthreads();
  if (ty < 6) {
    float a = 0.f;
#pragma unroll
    for (int k = 0; k < 8; k++) a += red2[ty][k][tx];
    atomicAdd(&out[((size_t)b * 10 + 4 + ty) * HW_ + n0 + tx], a);
  }
}

// 4 fine banks fp32 [b][m][c] -> bf16 stacked [g][b][m][c]
__global__ void convert_banks(const float* __restrict__ b0, const float* __restrict__ b1,
                              const float* __restrict__ b2, const float* __restrict__ b3,
                              unsigned short* __restrict__ out) {
  const size_t per = (size_t)B_ * HW_ * C_;
  int g = blockIdx.y;
  const float* src = (g == 0) ? b0 : (g == 1) ? b1 : (g == 2) ? b2 : b3;
  size_t i = ((size_t)blockIdx.x * blockDim.x + threadIdx.x) * 4;
  float4 v = *(const float4*)(src + i);
  ushort4 o;
  o.x = f2bf(v.x); o.y = f2bf(v.y); o.z = f2bf(v.z); o.w = f2bf(v.w);
  *(ushort4*)(out + g * per + i) = o;
}

// Fine scores, 32x32x16 MFMA, bank-paired, one 128x128 m-tile per block.
// Writes partial column max to pmax[mt][b][g][n].
__global__ __launch_bounds__(256, 3) void fine_kernel(
    const unsigned short* __restrict__ keyT,   // bf16 [b][n][c]
    const unsigned short* __restrict__ banks,  // bf16 [g][b][m][c]
    const float* __restrict__ sds,             // fp32 [b][m][n]
    float* __restrict__ pmax) {
  int nt = blockIdx.x % NT_;
  int mt = blockIdx.x / NT_;   // 0..17
  int gp = blockIdx.y;         // 0: banks 0,1 (unmasked)  1: banks 2,3 (masked)
  int b  = blockIdx.z;
  int n0 = nt * BN;
  int m0 = mt * BM;

  __shared__ __align__(16) unsigned short A0[BM * 64];  // 16 KB, XOR-swizzled
  __shared__ __align__(16) unsigned short A1[BM * 64];
  __shared__ __align__(16) unsigned short Bl[BN * 64];
  __shared__ float red[2][2][BN];                       // [bank][wm-half][col]

  int t     = threadIdx.x;
  int wave  = t >> 6;
  int lane  = t & 63;
  int l31   = lane & 31;
  int khalf = lane >> 5;       // k-half for 32x32x16 frags
  int l7    = l31 & 7;
  int wm    = (wave & 1) * 64;
  int wn    = (wave >> 1) * 64;

  // staging swizzle: lds row = rbase + (lane>>3), global k-sub = (lane&7)^(row&7)
  int srow = lane >> 3;
  int ssub = (lane & 7) ^ srow;

  // fragment reads: row r has r&7 == l7 for all tiles; slot = (ks*2+khalf)^l7
  int swz[4];
#pragma unroll
  for (int ks = 0; ks < 4; ks++) swz[ks] = ((ks * 2 + khalf) ^ l7) * 8;
  int rowA[2], rowB[2];
#pragma unroll
  for (int i = 0; i < 2; i++) {
    rowA[i] = (wm + i * 32 + l31) * 64;
    rowB[i] = (wn + i * 32 + l31) * 64;
  }

  const unsigned short* bank0 = banks + ((size_t)(2 * gp) * B_ + b) * (size_t)HW_ * C_;
  const unsigned short* bank1 = banks + ((size_t)(2 * gp + 1) * B_ + b) * (size_t)HW_ * C_;
  const unsigned short* keyb  = keyT + (size_t)b * HW_ * C_;
  const float* maskb = sds + (size_t)b * HW_ * HW_;
  const bool masked = (gp == 1);

  f32x16 acc0[2][2], acc1[2][2];
#pragma unroll
  for (int i = 0; i < 2; i++)
#pragma unroll
    for (int j = 0; j < 2; j++)
#pragma unroll
      for (int e = 0; e < 16; e++) { acc0[i][j][e] = 0.0f; acc1[i][j][e] = 0.0f; }

  for (int kc = 0; kc < C_ / BK; kc++) {
    __syncthreads();   // prior round's frag reads done before overwrite
#pragma unroll
    for (int j = 0; j < 4; j++) {
      int rbase = wave * 32 + j * 8;
      int row   = rbase + srow;
      size_t goff = (size_t)row * C_ + kc * BK + ssub * 8;
      gload_lds16(bank0 + (size_t)m0 * C_ + goff, &A0[rbase * 64]);
      gload_lds16(bank1 + (size_t)m0 * C_ + goff, &A1[rbase * 64]);
      gload_lds16(keyb  + (size_t)n0 * C_ + goff, &Bl[rbase * 64]);
    }
    __syncthreads();   // drains vmcnt before use
#pragma unroll
    for (int ks = 0; ks < 4; ks++) {
      int sw = swz[ks];
      bf16x8 a0[2], a1[2], bb[2];
#pragma unroll
      for (int ms = 0; ms < 2; ms++) {
        a0[ms] = *(const bf16x8*)(&A0[rowA[ms] + sw]);
        a1[ms] = *(const bf16x8*)(&A1[rowA[ms] + sw]);
      }
#pragma unroll
      for (int ns = 0; ns < 2; ns++)
        bb[ns] = *(const bf16x8*)(&Bl[rowB[ns] + sw]);
#pragma unroll
      for (int ms = 0; ms < 2; ms++)
#pragma unroll
        for (int ns = 0; ns < 2; ns++) {
          acc0[ms][ns] = __builtin_amdgcn_mfma_f32_32x32x16_bf16(
              a0[ms], bb[ns], acc0[ms][ns], 0, 0, 0);
          acc1[ms][ns] = __builtin_amdgcn_mfma_f32_32x32x16_bf16(
              a1[ms], bb[ns], acc1[ms][ns], 0, 0, 0);
        }
    }
  }

  // epilogue: C/D 32x32 layout: col = lane&31, row_local = (reg&3)+8*(reg>>2)+4*khalf
  float rm0[2], rm1[2];
#pragma unroll
  for (int i = 0; i < 2; i++) { rm0[i] = -3.4e38f; rm1[i] = -3.4e38f; }
#pragma unroll
  for (int ms = 0; ms < 2; ms++) {
#pragma unroll
    for (int ns = 0; ns < 2; ns++) {
      int n = n0 + wn + ns * 32 + l31;
#pragma unroll
      for (int reg = 0; reg < 16; reg++) {
        float s0 = acc0[ms][ns][reg];
        float s1 = acc1[ms][ns][reg];
        if (masked) {
          int ml = (reg & 3) + 8 * (reg >> 2) + 4 * khalf;
          float w = maskb[(size_t)(m0 + wm + ms * 32 + ml) * HW_ + n];
          s0 *= w; s1 *= w;
        }
        rm0[ns] = fmaxf(rm0[ns], s0);
        rm1[ns] = fmaxf(rm1[ns], s1);
      }
    }
  }

  // fold khalf halves (same column, different rows)
#pragma unroll
  for (int ns = 0; ns < 2; ns++) {
    rm0[ns] = fmaxf(rm0[ns], __shfl_xor(rm0[ns], 32, 64));
    rm1[ns] = fmaxf(rm1[ns], __shfl_xor(rm1[ns], 32, 64));
  }
  if (khalf == 0) {
#pragma unroll
    for (int ns = 0; ns < 2; ns++) {
      red[0][wave & 1][wn + ns * 32 + l31] = rm0[ns];
      red[1][wave & 1][wn + ns * 32 + l31] = rm1[ns];
    }
  }
  __syncthreads();
  if (t < BN) {
    float vv0 = fmaxf(red[0][0][t], red[0][1][t]);
    float vv1 = fmaxf(red[1][0][t], red[1][1][t]);
    pmax[(((size_t)mt * B_ + b) * 4 + 2 * gp)     * HW_ + n0 + t] = vv0;
    pmax[(((size_t)mt * B_ + b) * 4 + 2 * gp + 1) * HW_ + n0 + t] = vv1;
  }
}

// max over m-tiles -> out channels 0..3
__global__ void fine_combine(const float* __restrict__ pmax, float* __restrict__ out) {
  int i = blockIdx.x * 256 + threadIdx.x;   // over B_*4*HW_
  if (i >= B_ * 4 * HW_) return;
  int n = i % HW_;
  int g = (i / HW_) % 4;
  int b = i / (HW_ * 4);
  float v = -3.4e38f;
#pragma unroll
  for (int mc = 0; mc < MCHUNKS; mc++)
    v = fmaxf(v, pmax[(((size_t)mc * B_ + b) * 4 + g) * HW_ + n]);
  out[((size_t)b * 10 + g) * HW_ + n] = v;
}

extern "C" void kernel_launch(void* const* d_in, const int* in_sizes, int n_in,
                              void* d_out, int out_size, void* d_ws, size_t ws_size,
                              hipStream_t stream) {
  const float* key  = (const float*)d_in[0];
  const float* sds  = (const float*)d_in[1];
  const float* gbg  = (const float*)d_in[2];
  const float* gfg  = (const float*)d_in[3];
  const float* lbg  = (const float*)d_in[4];
  const float* lfg  = (const float*)d_in[5];
  const float* obg  = (const float*)d_in[6];
  const float* ofg  = (const float*)d_in[7];
  const float* sbg  = (const float*)d_in[8];
  const float* sfg  = (const float*)d_in[9];
  const float* lobg = (const float*)d_in[10];
  const float* lofg = (const float*)d_in[11];
  float* out = (float*)d_out;

  unsigned short* keyT  = (unsigned short*)d_ws;               // 18.9 MB
  unsigned short* banks = keyT + (size_t)B_ * HW_ * C_;        // +75.5 MB
  float* pmax = (float*)(banks + (size_t)4 * B_ * HW_ * C_);   // +5.3 MB (~99.7 MB)

  zero_out<<<(out_size + 255) / 256, 256, 0, stream>>>(out, out_size);
  convert_banks<<<dim3((B_ * HW_ * C_) / (4 * 256), 4), 256, 0, stream>>>(gbg, gfg, lbg, lfg, banks);
  transpose_coarse<<<dim3(HW_ / 32, C_ / 32, B_), dim3(32, 8), 0, stream>>>(
      key, obg, ofg, sbg, sfg, lobg, lofg, keyT, out);
  fine_kernel<<<dim3(NT_ * MCHUNKS, 2, B_), 256, 0, stream>>>(keyT, banks, sds, pmax);
  fine_combine<<<(B_ * 4 * HW_ + 255) / 256, 256, 0, stream>>>(pmax, out);
}